// Round 7
// baseline (1121.980 us; speedup 1.0000x reference)
//
#include <hip/hip_runtime.h>
#include <hip/hip_cooperative_groups.h>
#include <math.h>

namespace cg = cooperative_groups;

#define H      300
#define NLEAF  4096
#define NTHR   320

__device__ __forceinline__ float sigmoidf_(float x) { return 1.0f / (1.0f + expf(-x)); }

// Load next 8 weight rows (2 consecutive cols) from wp, advance wp.
__device__ __forceinline__ void ldw8(const float*& wp, float2* w)
{
    #pragma unroll
    for (int i = 0; i < 8; ++i) w[i] = *(const float2*)&wp[i * H];
    wp += 8 * H;
}

// 8 k-steps x 2 cols of FMA for NN nodes starting at X row jbase.
template<int NN, int XW>
__device__ __forceinline__ void fma8(const float2* w, const float (*X)[XW],
                                     int jbase, int d, float* a0, float* a1)
{
    #pragma unroll
    for (int j = 0; j < NN; ++j) {
        float4 xlo = *(const float4*)&X[jbase + j][d];
        float4 xhi = *(const float4*)&X[jbase + j][d + 4];
        a0[j] = fmaf(xlo.x, w[0].x, a0[j]); a1[j] = fmaf(xlo.x, w[0].y, a1[j]);
        a0[j] = fmaf(xlo.y, w[1].x, a0[j]); a1[j] = fmaf(xlo.y, w[1].y, a1[j]);
        a0[j] = fmaf(xlo.z, w[2].x, a0[j]); a1[j] = fmaf(xlo.z, w[2].y, a1[j]);
        a0[j] = fmaf(xlo.w, w[3].x, a0[j]); a1[j] = fmaf(xlo.w, w[3].y, a1[j]);
        a0[j] = fmaf(xhi.x, w[4].x, a0[j]); a1[j] = fmaf(xhi.x, w[4].y, a1[j]);
        a0[j] = fmaf(xhi.y, w[5].x, a0[j]); a1[j] = fmaf(xhi.y, w[5].y, a1[j]);
        a0[j] = fmaf(xhi.z, w[6].x, a0[j]); a1[j] = fmaf(xhi.z, w[6].y, a1[j]);
        a0[j] = fmaf(xhi.w, w[7].x, a0[j]); a1[j] = fmaf(xhi.w, w[7].y, a1[j]);
    }
}

// Depth-4 software-pipelined GEMM over NCH chunks of 8 K-rows.
// All buffer indices static (4x-unrolled body + constexpr-tail epilogue).
template<int NCH, int NN, int XW>
__device__ __forceinline__ void gemm_pipe(const float* wp, const float (*X)[XW],
                                          int jbase, float* a0, float* a1)
{
    float2 w0[8], w1[8], w2[8], w3[8];
    ldw8(wp, w0); ldw8(wp, w1); ldw8(wp, w2);
    int d = 0;
    constexpr int IT = (NCH - 3) / 4;
    constexpr int L  = (NCH - 3) - 4 * IT;
    for (int it = 0; it < IT; ++it) {
        ldw8(wp, w3); fma8<NN, XW>(w0, X, jbase, d,      a0, a1);
        ldw8(wp, w0); fma8<NN, XW>(w1, X, jbase, d + 8,  a0, a1);
        ldw8(wp, w1); fma8<NN, XW>(w2, X, jbase, d + 16, a0, a1);
        ldw8(wp, w2); fma8<NN, XW>(w3, X, jbase, d + 24, a0, a1);
        d += 32;
    }
    if constexpr (L == 0) {
        fma8<NN, XW>(w0, X, jbase, d,      a0, a1);
        fma8<NN, XW>(w1, X, jbase, d + 8,  a0, a1);
        fma8<NN, XW>(w2, X, jbase, d + 16, a0, a1);
    } else if constexpr (L == 1) {
        ldw8(wp, w3);
        fma8<NN, XW>(w0, X, jbase, d,      a0, a1);
        fma8<NN, XW>(w1, X, jbase, d + 8,  a0, a1);
        fma8<NN, XW>(w2, X, jbase, d + 16, a0, a1);
        fma8<NN, XW>(w3, X, jbase, d + 24, a0, a1);
    } else if constexpr (L == 2) {
        ldw8(wp, w3); fma8<NN, XW>(w0, X, jbase, d,      a0, a1);
        ldw8(wp, w0); fma8<NN, XW>(w1, X, jbase, d + 8,  a0, a1);
        fma8<NN, XW>(w2, X, jbase, d + 16, a0, a1);
        fma8<NN, XW>(w3, X, jbase, d + 24, a0, a1);
        fma8<NN, XW>(w0, X, jbase, d + 32, a0, a1);
    } else {
        ldw8(wp, w3); fma8<NN, XW>(w0, X, jbase, d,      a0, a1);
        ldw8(wp, w0); fma8<NN, XW>(w1, X, jbase, d + 8,  a0, a1);
        ldw8(wp, w1); fma8<NN, XW>(w2, X, jbase, d + 16, a0, a1);
        fma8<NN, XW>(w3, X, jbase, d + 24, a0, a1);
        fma8<NN, XW>(w0, X, jbase, d + 32, a0, a1);
        fma8<NN, XW>(w1, X, jbase, d + 40, a0, a1);
    }
}

// tag_r[t][k] = br[k] + sum_j tag_table[t][j] * Wr[300+j][k]   (likewise tag_z)
__global__ __launch_bounds__(320) void tag_kernel(
    const float* __restrict__ tag_table,
    const float* __restrict__ Wr, const float* __restrict__ br,
    const float* __restrict__ Wz, const float* __restrict__ bz,
    float* __restrict__ tag_r, float* __restrict__ tag_z)
{
    int t = blockIdx.x;
    int k = threadIdx.x;
    __shared__ float te[50];
    if (k < 50) te[k] = tag_table[t * 50 + k];
    __syncthreads();
    if (k < H) {
        float ar = br[k], az = bz[k];
        #pragma unroll 10
        for (int j = 0; j < 50; ++j) {
            float tv = te[j];
            ar = fmaf(tv, Wr[(H + j) * H + k], ar);
            az = fmaf(tv, Wz[(H + j) * H + k], az);
        }
        tag_r[t * H + k] = ar;
        tag_z[t * H + k] = az;
    }
}

// Leaf: lh=rh=0 => r unused; h = (1-z)*u
// K padded 300->304 (38 chunks of 8); X[.][300..303]=0, extra weight rows
// (valid memory in Wz[950x300]/Wu[900x300]) multiply exact zeros.
template<int NB>
__global__ __launch_bounds__(NTHR, 1) void leaf_k(
    const int* __restrict__ word_ids, const int* __restrict__ tag_ids,
    const float* __restrict__ word_table,
    const float* __restrict__ Wz, const float* __restrict__ Wu,
    const float* __restrict__ bu, const float* __restrict__ tag_z,
    float* __restrict__ out)
{
    __shared__ float X[NB][H + 4];    // 304 floats; [300..303] zeroed
    __shared__ float Zs[NB][H + 4];
    int node0 = blockIdx.x * NB;
    int tid = threadIdx.x;

    for (int idx = tid; idx < NB * 75; idx += NTHR) {
        int j = idx / 75, q = idx - j * 75;
        *(float4*)&X[j][q * 4] =
            *(const float4*)&word_table[(long)word_ids[node0 + j] * H + q * 4];
    }
    if (tid < NB) *(float4*)&X[tid][H] = make_float4(0.f, 0.f, 0.f, 0.f);
    __syncthreads();

    int t = tid;
    int isu = (t >= 150);
    int c0 = 2 * (t - 150 * isu);
    float acc0[NB], acc1[NB];
    if (t < 300) {
        #pragma unroll
        for (int j = 0; j < NB; ++j) { acc0[j] = 0.f; acc1[j] = 0.f; }
        gemm_pipe<38, NB, H + 4>((isu ? Wu : Wz) + c0, X, 0, acc0, acc1);
        if (!isu) {
            #pragma unroll
            for (int j = 0; j < NB; ++j) {
                int tg = tag_ids[node0 + j];
                Zs[j][c0]     = sigmoidf_(acc0[j] + tag_z[tg * H + c0]);
                Zs[j][c0 + 1] = sigmoidf_(acc1[j] + tag_z[tg * H + c0 + 1]);
            }
        }
    }
    __syncthreads();
    if (t >= 150 && t < 300) {
        float b0 = bu[c0], b1 = bu[c0 + 1];
        #pragma unroll
        for (int j = 0; j < NB; ++j) {
            float u0 = tanhf(acc0[j] + b0);
            float u1 = tanhf(acc1[j] + b1);
            float h0 = (1.f - Zs[j][c0]) * u0;
            float h1 = (1.f - Zs[j][c0 + 1]) * u1;
            *(float2*)&out[(long)(node0 + j) * H + c0] = make_float2(h0, h1);
        }
    }
}

// Internal-level body (one block's NB nodes). we=0; K=600 (75 chunks of 8).
// A: pre_r = [lh|rh]@Wr[350:950]+tag_r ; pre_z likewise (Wz). r,z=sigmoid.
// B: u = tanh([r*lh|r*rh]@Wu[300:900]+bu); h = z*(lh+rh)+(1-z)*u
// dup: if non-null, mirror node (off+0)'s h there (final_state).
template<int NB>
__device__ __forceinline__ void level_body(
    const int* __restrict__ tag_ids,
    const float* __restrict__ Wr, const float* __restrict__ Wz,
    const float* __restrict__ Wu, const float* __restrict__ bu,
    const float* __restrict__ tag_r, const float* __restrict__ tag_z,
    float* __restrict__ out, int off, int prevOff, float* __restrict__ dup,
    int node0, int tid,
    float (*X)[2 * H + 8], float (*Ss)[H + 4], float (*Zs)[H + 4])
{
    for (int idx = tid; idx < NB * 150; idx += NTHR) {
        int j = idx / 150, q = idx - j * 150;
        int half = q / 75, qq = q - half * 75;
        *(float4*)&X[j][half * H + qq * 4] =
            *(const float4*)&out[(long)(prevOff + 2 * (node0 + j) + half) * H + qq * 4];
    }
    __syncthreads();

    int t = tid;
    int isz = (t >= 150);
    int c0 = 2 * (t - 150 * isz);
    float acc0[NB], acc1[NB];
    if (t < 300) {
        #pragma unroll
        for (int j = 0; j < NB; ++j) { acc0[j] = 0.f; acc1[j] = 0.f; }
        gemm_pipe<75, NB, 2 * H + 8>(((isz ? Wz : Wr) + 350 * H) + c0, X, 0, acc0, acc1);
    }
    __syncthreads();   // all GEMM reads of X complete before in-place scale

    if (t < 300) {
        if (!isz) {
            #pragma unroll
            for (int j = 0; j < NB; ++j) {
                int tg = tag_ids[off + node0 + j];
                float r0 = sigmoidf_(acc0[j] + tag_r[tg * H + c0]);
                float r1 = sigmoidf_(acc1[j] + tag_r[tg * H + c0 + 1]);
                float l0 = X[j][c0], l1 = X[j][c0 + 1];
                float q0 = X[j][H + c0], q1 = X[j][H + c0 + 1];
                Ss[j][c0]     = l0 + q0;
                Ss[j][c0 + 1] = l1 + q1;
                X[j][c0]     = r0 * l0;  X[j][c0 + 1] = r1 * l1;
                X[j][H + c0] = r0 * q0;  X[j][H + c0 + 1] = r1 * q1;
            }
        } else {
            #pragma unroll
            for (int j = 0; j < NB; ++j) {
                int tg = tag_ids[off + node0 + j];
                Zs[j][c0]     = sigmoidf_(acc0[j] + tag_z[tg * H + c0]);
                Zs[j][c0 + 1] = sigmoidf_(acc1[j] + tag_z[tg * H + c0 + 1]);
            }
        }
    }
    __syncthreads();

    // Phase B: split nodes between the two 150-thread groups (if NB>1)
    constexpr int NBB = (NB > 1) ? NB / 2 : 1;
    int jb = (NB > 1) ? isz * NBB : 0;
    bool actB = (t < 300) && (NB > 1 || !isz);
    if (actB) {
        float b0a[NBB], b1a[NBB];
        #pragma unroll
        for (int jj = 0; jj < NBB; ++jj) { b0a[jj] = 0.f; b1a[jj] = 0.f; }
        gemm_pipe<75, NBB, 2 * H + 8>((Wu + 300 * H) + c0, X, jb, b0a, b1a);
        float bb0 = bu[c0], bb1 = bu[c0 + 1];
        #pragma unroll
        for (int jj = 0; jj < NBB; ++jj) {
            int j = jb + jj;
            float u0 = tanhf(b0a[jj] + bb0);
            float u1 = tanhf(b1a[jj] + bb1);
            float z0 = Zs[j][c0], z1 = Zs[j][c0 + 1];
            float h0 = z0 * Ss[j][c0]     + (1.f - z0) * u0;
            float h1 = z1 * Ss[j][c0 + 1] + (1.f - z1) * u1;
            *(float2*)&out[(long)(off + node0 + j) * H + c0] = make_float2(h0, h1);
            if (dup && node0 + j == 0)
                *(float2*)&dup[c0] = make_float2(h0, h1);
        }
    }
}

template<int NB>
__global__ __launch_bounds__(NTHR, 1) void level_k(
    const int* __restrict__ tag_ids,
    const float* __restrict__ Wr, const float* __restrict__ Wz,
    const float* __restrict__ Wu, const float* __restrict__ bu,
    const float* __restrict__ tag_r, const float* __restrict__ tag_z,
    float* __restrict__ out, int off, int prevOff)
{
    __shared__ float X[NB][2 * H + 8];
    __shared__ float Ss[NB][H + 4];
    __shared__ float Zs[NB][H + 4];
    level_body<NB>(tag_ids, Wr, Wz, Wu, bu, tag_r, tag_z, out, off, prevOff,
                   nullptr, blockIdx.x * NB, threadIdx.x, X, Ss, Zs);
}

// Cooperative tail: levels m=256..1 (511 nodes) in ONE launch.
// 256 blocks; block b handles node b of each level (idle if b >= m).
__global__ __launch_bounds__(NTHR, 1) void tail_coop(
    const int* __restrict__ tag_ids,
    const float* __restrict__ Wr, const float* __restrict__ Wz,
    const float* __restrict__ Wu, const float* __restrict__ bu,
    const float* __restrict__ tag_r, const float* __restrict__ tag_z,
    float* __restrict__ out, float* __restrict__ finalDup)
{
    __shared__ float X[1][2 * H + 8];
    __shared__ float Ss[1][H + 4];
    __shared__ float Zs[1][H + 4];
    cg::grid_group grid = cg::this_grid();

    int off = 7680, prevOff = 7168;          // m=256 level offsets
    for (int m = 256; m >= 1; m >>= 1) {
        if ((int)blockIdx.x < m) {
            level_body<1>(tag_ids, Wr, Wz, Wu, bu, tag_r, tag_z, out, off,
                          prevOff, (m == 1) ? finalDup : nullptr,
                          blockIdx.x, threadIdx.x, X, Ss, Zs);
        }
        __threadfence();
        grid.sync();
        prevOff = off;
        off += m;
    }
}

extern "C" void kernel_launch(void* const* d_in, const int* in_sizes, int n_in,
                              void* d_out, int out_size, void* d_ws, size_t ws_size,
                              hipStream_t stream)
{
    const int*   word_ids   = (const int*)  d_in[0];
    const int*   tag_ids    = (const int*)  d_in[1];
    const float* word_table = (const float*)d_in[2];
    const float* tag_table  = (const float*)d_in[3];
    const float* Wr         = (const float*)d_in[4];
    const float* br         = (const float*)d_in[5];
    const float* Wz         = (const float*)d_in[6];
    const float* bz         = (const float*)d_in[7];
    const float* Wu         = (const float*)d_in[8];
    const float* bu         = (const float*)d_in[9];
    float* out = (float*)d_out;

    float* tag_r = (float*)d_ws;
    float* tag_z = tag_r + 60 * H;

    tag_kernel<<<60, 320, 0, stream>>>(tag_table, Wr, br, Wz, bz, tag_r, tag_z);

    leaf_k<8><<<NLEAF / 8, NTHR, 0, stream>>>(
        word_ids, tag_ids, word_table, Wz, Wu, bu, tag_z, out);

    // Big internal levels: target 2 blocks/CU (grid 512)
    level_k<4><<<512, NTHR, 0, stream>>>(tag_ids, Wr, Wz, Wu, bu, tag_r, tag_z, out, 4096, 0);
    level_k<2><<<512, NTHR, 0, stream>>>(tag_ids, Wr, Wz, Wu, bu, tag_r, tag_z, out, 6144, 4096);
    level_k<1><<<512, NTHR, 0, stream>>>(tag_ids, Wr, Wz, Wu, bu, tag_r, tag_z, out, 7168, 6144);

    // Tail levels m=256..1 in one cooperative launch
    float* finalDup = out + (long)8191 * H;
    void* args[] = {
        (void*)&tag_ids, (void*)&Wr, (void*)&Wz, (void*)&Wu, (void*)&bu,
        (void*)&tag_r, (void*)&tag_z, (void*)&out, (void*)&finalDup
    };
    hipLaunchCooperativeKernel((void*)tail_coop, dim3(256), dim3(NTHR),
                               args, 0, stream);
}

// Round 8
// 759.279 us; speedup vs baseline: 1.4777x; 1.4777x over previous
//
#include <hip/hip_runtime.h>
#include <math.h>

#define H      300
#define NLEAF  4096
#define NTHR   320

__device__ __forceinline__ float sigmoidf_(float x) { return 1.0f / (1.0f + expf(-x)); }

// Load next 8 weight rows (2 consecutive cols) from wp, advance wp.
__device__ __forceinline__ void ldw8(const float*& wp, float2* w)
{
    #pragma unroll
    for (int i = 0; i < 8; ++i) w[i] = *(const float2*)&wp[i * H];
    wp += 8 * H;
}

// 8 k-steps x 2 cols of FMA for NN nodes starting at X row jbase.
template<int NN, int XW>
__device__ __forceinline__ void fma8(const float2* w, const float (*X)[XW],
                                     int jbase, int d, float* a0, float* a1)
{
    #pragma unroll
    for (int j = 0; j < NN; ++j) {
        float4 xlo = *(const float4*)&X[jbase + j][d];
        float4 xhi = *(const float4*)&X[jbase + j][d + 4];
        a0[j] = fmaf(xlo.x, w[0].x, a0[j]); a1[j] = fmaf(xlo.x, w[0].y, a1[j]);
        a0[j] = fmaf(xlo.y, w[1].x, a0[j]); a1[j] = fmaf(xlo.y, w[1].y, a1[j]);
        a0[j] = fmaf(xlo.z, w[2].x, a0[j]); a1[j] = fmaf(xlo.z, w[2].y, a1[j]);
        a0[j] = fmaf(xlo.w, w[3].x, a0[j]); a1[j] = fmaf(xlo.w, w[3].y, a1[j]);
        a0[j] = fmaf(xhi.x, w[4].x, a0[j]); a1[j] = fmaf(xhi.x, w[4].y, a1[j]);
        a0[j] = fmaf(xhi.y, w[5].x, a0[j]); a1[j] = fmaf(xhi.y, w[5].y, a1[j]);
        a0[j] = fmaf(xhi.z, w[6].x, a0[j]); a1[j] = fmaf(xhi.z, w[6].y, a1[j]);
        a0[j] = fmaf(xhi.w, w[7].x, a0[j]); a1[j] = fmaf(xhi.w, w[7].y, a1[j]);
    }
}

// Depth-4 software-pipelined GEMM over NCH chunks of 8 K-rows.
// All buffer indices static (4x-unrolled body + constexpr-tail epilogue).
template<int NCH, int NN, int XW>
__device__ __forceinline__ void gemm_pipe(const float* wp, const float (*X)[XW],
                                          int jbase, float* a0, float* a1)
{
    float2 w0[8], w1[8], w2[8], w3[8];
    ldw8(wp, w0); ldw8(wp, w1); ldw8(wp, w2);
    int d = 0;
    constexpr int IT = (NCH - 3) / 4;
    constexpr int L  = (NCH - 3) - 4 * IT;
    for (int it = 0; it < IT; ++it) {
        ldw8(wp, w3); fma8<NN, XW>(w0, X, jbase, d,      a0, a1);
        ldw8(wp, w0); fma8<NN, XW>(w1, X, jbase, d + 8,  a0, a1);
        ldw8(wp, w1); fma8<NN, XW>(w2, X, jbase, d + 16, a0, a1);
        ldw8(wp, w2); fma8<NN, XW>(w3, X, jbase, d + 24, a0, a1);
        d += 32;
    }
    if constexpr (L == 0) {
        fma8<NN, XW>(w0, X, jbase, d,      a0, a1);
        fma8<NN, XW>(w1, X, jbase, d + 8,  a0, a1);
        fma8<NN, XW>(w2, X, jbase, d + 16, a0, a1);
    } else if constexpr (L == 1) {
        ldw8(wp, w3);
        fma8<NN, XW>(w0, X, jbase, d,      a0, a1);
        fma8<NN, XW>(w1, X, jbase, d + 8,  a0, a1);
        fma8<NN, XW>(w2, X, jbase, d + 16, a0, a1);
        fma8<NN, XW>(w3, X, jbase, d + 24, a0, a1);
    } else if constexpr (L == 2) {
        ldw8(wp, w3); fma8<NN, XW>(w0, X, jbase, d,      a0, a1);
        ldw8(wp, w0); fma8<NN, XW>(w1, X, jbase, d + 8,  a0, a1);
        fma8<NN, XW>(w2, X, jbase, d + 16, a0, a1);
        fma8<NN, XW>(w3, X, jbase, d + 24, a0, a1);
        fma8<NN, XW>(w0, X, jbase, d + 32, a0, a1);
    } else {
        ldw8(wp, w3); fma8<NN, XW>(w0, X, jbase, d,      a0, a1);
        ldw8(wp, w0); fma8<NN, XW>(w1, X, jbase, d + 8,  a0, a1);
        ldw8(wp, w1); fma8<NN, XW>(w2, X, jbase, d + 16, a0, a1);
        fma8<NN, XW>(w3, X, jbase, d + 24, a0, a1);
        fma8<NN, XW>(w0, X, jbase, d + 32, a0, a1);
        fma8<NN, XW>(w1, X, jbase, d + 40, a0, a1);
    }
}

// tag_r[t][k] = br[k] + sum_j tag_table[t][j] * Wr[300+j][k]   (likewise tag_z)
__global__ __launch_bounds__(320) void tag_kernel(
    const float* __restrict__ tag_table,
    const float* __restrict__ Wr, const float* __restrict__ br,
    const float* __restrict__ Wz, const float* __restrict__ bz,
    float* __restrict__ tag_r, float* __restrict__ tag_z)
{
    int t = blockIdx.x;
    int k = threadIdx.x;
    __shared__ float te[50];
    if (k < 50) te[k] = tag_table[t * 50 + k];
    __syncthreads();
    if (k < H) {
        float ar = br[k], az = bz[k];
        #pragma unroll 10
        for (int j = 0; j < 50; ++j) {
            float tv = te[j];
            ar = fmaf(tv, Wr[(H + j) * H + k], ar);
            az = fmaf(tv, Wz[(H + j) * H + k], az);
        }
        tag_r[t * H + k] = ar;
        tag_z[t * H + k] = az;
    }
}

// Leaf: lh=rh=0 => r unused; h = (1-z)*u
// K padded 300->304 (38 chunks of 8); X[.][300..303]=0, extra weight rows
// (valid memory in Wz[950x300]/Wu[900x300]) multiply exact zeros.
template<int NB>
__global__ __launch_bounds__(NTHR, 1) void leaf_k(
    const int* __restrict__ word_ids, const int* __restrict__ tag_ids,
    const float* __restrict__ word_table,
    const float* __restrict__ Wz, const float* __restrict__ Wu,
    const float* __restrict__ bu, const float* __restrict__ tag_z,
    float* __restrict__ out)
{
    __shared__ float X[NB][H + 4];    // 304 floats; [300..303] zeroed
    __shared__ float Zs[NB][H + 4];
    int node0 = blockIdx.x * NB;
    int tid = threadIdx.x;

    for (int idx = tid; idx < NB * 75; idx += NTHR) {
        int j = idx / 75, q = idx - j * 75;
        *(float4*)&X[j][q * 4] =
            *(const float4*)&word_table[(long)word_ids[node0 + j] * H + q * 4];
    }
    if (tid < NB) *(float4*)&X[tid][H] = make_float4(0.f, 0.f, 0.f, 0.f);
    __syncthreads();

    int t = tid;
    int isu = (t >= 150);
    int c0 = 2 * (t - 150 * isu);
    float acc0[NB], acc1[NB];
    if (t < 300) {
        #pragma unroll
        for (int j = 0; j < NB; ++j) { acc0[j] = 0.f; acc1[j] = 0.f; }
        gemm_pipe<38, NB, H + 4>((isu ? Wu : Wz) + c0, X, 0, acc0, acc1);
        if (!isu) {
            #pragma unroll
            for (int j = 0; j < NB; ++j) {
                int tg = tag_ids[node0 + j];
                Zs[j][c0]     = sigmoidf_(acc0[j] + tag_z[tg * H + c0]);
                Zs[j][c0 + 1] = sigmoidf_(acc1[j] + tag_z[tg * H + c0 + 1]);
            }
        }
    }
    __syncthreads();
    if (t >= 150 && t < 300) {
        float b0 = bu[c0], b1 = bu[c0 + 1];
        #pragma unroll
        for (int j = 0; j < NB; ++j) {
            float u0 = tanhf(acc0[j] + b0);
            float u1 = tanhf(acc1[j] + b1);
            float h0 = (1.f - Zs[j][c0]) * u0;
            float h1 = (1.f - Zs[j][c0 + 1]) * u1;
            *(float2*)&out[(long)(node0 + j) * H + c0] = make_float2(h0, h1);
        }
    }
}

// Internal-level body (one block's NB nodes). we=0; K=600 (75 chunks of 8).
// A: pre_r = [lh|rh]@Wr[350:950]+tag_r ; pre_z likewise (Wz). r,z=sigmoid.
// B: u = tanh([r*lh|r*rh]@Wu[300:900]+bu); h = z*(lh+rh)+(1-z)*u
// dup: if non-null, mirror node (off+0)'s h there (final_state).
// Shared buffers passed in have row widths of the MAX NB user; row count >= NB.
template<int NB>
__device__ __forceinline__ void level_body(
    const int* __restrict__ tag_ids,
    const float* __restrict__ Wr, const float* __restrict__ Wz,
    const float* __restrict__ Wu, const float* __restrict__ bu,
    const float* __restrict__ tag_r, const float* __restrict__ tag_z,
    float* __restrict__ out, int off, int prevOff, float* __restrict__ dup,
    int node0, int tid,
    float (*X)[2 * H + 8], float (*Ss)[H + 4], float (*Zs)[H + 4])
{
    for (int idx = tid; idx < NB * 150; idx += NTHR) {
        int j = idx / 150, q = idx - j * 150;
        int half = q / 75, qq = q - half * 75;
        *(float4*)&X[j][half * H + qq * 4] =
            *(const float4*)&out[(long)(prevOff + 2 * (node0 + j) + half) * H + qq * 4];
    }
    __syncthreads();

    int t = tid;
    int isz = (t >= 150);
    int c0 = 2 * (t - 150 * isz);
    float acc0[NB], acc1[NB];
    if (t < 300) {
        #pragma unroll
        for (int j = 0; j < NB; ++j) { acc0[j] = 0.f; acc1[j] = 0.f; }
        gemm_pipe<75, NB, 2 * H + 8>(((isz ? Wz : Wr) + 350 * H) + c0, X, 0, acc0, acc1);
    }
    __syncthreads();   // all GEMM reads of X complete before in-place scale

    if (t < 300) {
        if (!isz) {
            #pragma unroll
            for (int j = 0; j < NB; ++j) {
                int tg = tag_ids[off + node0 + j];
                float r0 = sigmoidf_(acc0[j] + tag_r[tg * H + c0]);
                float r1 = sigmoidf_(acc1[j] + tag_r[tg * H + c0 + 1]);
                float l0 = X[j][c0], l1 = X[j][c0 + 1];
                float q0 = X[j][H + c0], q1 = X[j][H + c0 + 1];
                Ss[j][c0]     = l0 + q0;
                Ss[j][c0 + 1] = l1 + q1;
                X[j][c0]     = r0 * l0;  X[j][c0 + 1] = r1 * l1;
                X[j][H + c0] = r0 * q0;  X[j][H + c0 + 1] = r1 * q1;
            }
        } else {
            #pragma unroll
            for (int j = 0; j < NB; ++j) {
                int tg = tag_ids[off + node0 + j];
                Zs[j][c0]     = sigmoidf_(acc0[j] + tag_z[tg * H + c0]);
                Zs[j][c0 + 1] = sigmoidf_(acc1[j] + tag_z[tg * H + c0 + 1]);
            }
        }
    }
    __syncthreads();

    // Phase B: split nodes between the two 150-thread groups (if NB>1)
    constexpr int NBB = (NB > 1) ? NB / 2 : 1;
    int jb = (NB > 1) ? isz * NBB : 0;
    bool actB = (t < 300) && (NB > 1 || !isz);
    if (actB) {
        float b0a[NBB], b1a[NBB];
        #pragma unroll
        for (int jj = 0; jj < NBB; ++jj) { b0a[jj] = 0.f; b1a[jj] = 0.f; }
        gemm_pipe<75, NBB, 2 * H + 8>((Wu + 300 * H) + c0, X, jb, b0a, b1a);
        float bb0 = bu[c0], bb1 = bu[c0 + 1];
        #pragma unroll
        for (int jj = 0; jj < NBB; ++jj) {
            int j = jb + jj;
            float u0 = tanhf(b0a[jj] + bb0);
            float u1 = tanhf(b1a[jj] + bb1);
            float z0 = Zs[j][c0], z1 = Zs[j][c0 + 1];
            float h0 = z0 * Ss[j][c0]     + (1.f - z0) * u0;
            float h1 = z1 * Ss[j][c0 + 1] + (1.f - z1) * u1;
            *(float2*)&out[(long)(off + node0 + j) * H + c0] = make_float2(h0, h1);
            if (dup && node0 + j == 0)
                *(float2*)&dup[c0] = make_float2(h0, h1);
        }
    }
}

template<int NB>
__global__ __launch_bounds__(NTHR, 1) void level_k(
    const int* __restrict__ tag_ids,
    const float* __restrict__ Wr, const float* __restrict__ Wz,
    const float* __restrict__ Wu, const float* __restrict__ bu,
    const float* __restrict__ tag_r, const float* __restrict__ tag_z,
    float* __restrict__ out, int off, int prevOff)
{
    __shared__ float X[NB][2 * H + 8];
    __shared__ float Ss[NB][H + 4];
    __shared__ float Zs[NB][H + 4];
    level_body<NB>(tag_ids, Wr, Wz, Wu, bu, tag_r, tag_z, out, off, prevOff,
                   nullptr, blockIdx.x * NB, threadIdx.x, X, Ss, Zs);
}

// Fused 3-level subtree kernel: levels of size M0, M0/2, M0/4 where
// grid = M0/4 blocks. Block b owns nodes {4b..4b+3}, {2b,2b+1}, {b} — all
// dependencies in-block, so only __syncthreads() between stages
// (__syncthreads guarantees intra-block visibility of prior global writes).
// dup applied at the last stage if dupEn and node is global node 0 of it.
__global__ __launch_bounds__(NTHR, 1) void tail3_k(
    const int* __restrict__ tag_ids,
    const float* __restrict__ Wr, const float* __restrict__ Wz,
    const float* __restrict__ Wu, const float* __restrict__ bu,
    const float* __restrict__ tag_r, const float* __restrict__ tag_z,
    float* __restrict__ out, int off0, int prevOff0, int m0,
    float* __restrict__ dup)
{
    __shared__ float X[4][2 * H + 8];
    __shared__ float Ss[4][H + 4];
    __shared__ float Zs[4][H + 4];
    int tid = threadIdx.x;
    int b = blockIdx.x;

    int off1 = off0 + m0, off2 = off1 + m0 / 2;

    level_body<4>(tag_ids, Wr, Wz, Wu, bu, tag_r, tag_z, out,
                  off0, prevOff0, nullptr, b * 4, tid, X, Ss, Zs);
    __syncthreads();
    level_body<2>(tag_ids, Wr, Wz, Wu, bu, tag_r, tag_z, out,
                  off1, off0, nullptr, b * 2, tid, X, Ss, Zs);
    __syncthreads();
    level_body<1>(tag_ids, Wr, Wz, Wu, bu, tag_r, tag_z, out,
                  off2, off1, dup, b, tid, X, Ss, Zs);
}

extern "C" void kernel_launch(void* const* d_in, const int* in_sizes, int n_in,
                              void* d_out, int out_size, void* d_ws, size_t ws_size,
                              hipStream_t stream)
{
    const int*   word_ids   = (const int*)  d_in[0];
    const int*   tag_ids    = (const int*)  d_in[1];
    const float* word_table = (const float*)d_in[2];
    const float* tag_table  = (const float*)d_in[3];
    const float* Wr         = (const float*)d_in[4];
    const float* br         = (const float*)d_in[5];
    const float* Wz         = (const float*)d_in[6];
    const float* bz         = (const float*)d_in[7];
    const float* Wu         = (const float*)d_in[8];
    const float* bu         = (const float*)d_in[9];
    float* out = (float*)d_out;

    float* tag_r = (float*)d_ws;
    float* tag_z = tag_r + 60 * H;

    tag_kernel<<<60, 320, 0, stream>>>(tag_table, Wr, br, Wz, bz, tag_r, tag_z);

    leaf_k<8><<<NLEAF / 8, NTHR, 0, stream>>>(
        word_ids, tag_ids, word_table, Wz, Wu, bu, tag_z, out);

    // Big internal levels: 2 blocks/CU (grid 512)
    level_k<4><<<512, NTHR, 0, stream>>>(tag_ids, Wr, Wz, Wu, bu, tag_r, tag_z, out, 4096, 0);
    level_k<2><<<512, NTHR, 0, stream>>>(tag_ids, Wr, Wz, Wu, bu, tag_r, tag_z, out, 6144, 4096);
    level_k<1><<<512, NTHR, 0, stream>>>(tag_ids, Wr, Wz, Wu, bu, tag_r, tag_z, out, 7168, 6144);

    // Tail: 9 levels (m=256..1) as 3 fused subtree launches
    float* finalDup = out + (long)8191 * H;
    tail3_k<<<64, NTHR, 0, stream>>>(tag_ids, Wr, Wz, Wu, bu, tag_r, tag_z,
                                     out, 7680, 7168, 256, nullptr);
    tail3_k<<<8,  NTHR, 0, stream>>>(tag_ids, Wr, Wz, Wu, bu, tag_r, tag_z,
                                     out, 8128, 8064, 32, nullptr);
    tail3_k<<<1,  NTHR, 0, stream>>>(tag_ids, Wr, Wz, Wu, bu, tag_r, tag_z,
                                     out, 8184, 8176, 4, finalDup);
}

// Round 9
// 545.636 us; speedup vs baseline: 2.0563x; 1.3915x over previous
//
#include <hip/hip_runtime.h>
#include <math.h>

#define H      300
#define NLEAF  4096
#define NTHR   320

__device__ __forceinline__ float sigmoidf_(float x) { return 1.0f / (1.0f + expf(-x)); }

// Load next 8 weight rows (2 consecutive cols) from wp, advance wp.
__device__ __forceinline__ void ldw8(const float*& wp, float2* w)
{
    #pragma unroll
    for (int i = 0; i < 8; ++i) w[i] = *(const float2*)&wp[i * H];
    wp += 8 * H;
}

// 8 k-steps x 2 cols of FMA for NN nodes starting at X row jbase.
template<int NN, int XW>
__device__ __forceinline__ void fma8(const float2* w, const float (*X)[XW],
                                     int jbase, int d, float* a0, float* a1)
{
    #pragma unroll
    for (int j = 0; j < NN; ++j) {
        float4 xlo = *(const float4*)&X[jbase + j][d];
        float4 xhi = *(const float4*)&X[jbase + j][d + 4];
        a0[j] = fmaf(xlo.x, w[0].x, a0[j]); a1[j] = fmaf(xlo.x, w[0].y, a1[j]);
        a0[j] = fmaf(xlo.y, w[1].x, a0[j]); a1[j] = fmaf(xlo.y, w[1].y, a1[j]);
        a0[j] = fmaf(xlo.z, w[2].x, a0[j]); a1[j] = fmaf(xlo.z, w[2].y, a1[j]);
        a0[j] = fmaf(xlo.w, w[3].x, a0[j]); a1[j] = fmaf(xlo.w, w[3].y, a1[j]);
        a0[j] = fmaf(xhi.x, w[4].x, a0[j]); a1[j] = fmaf(xhi.x, w[4].y, a1[j]);
        a0[j] = fmaf(xhi.y, w[5].x, a0[j]); a1[j] = fmaf(xhi.y, w[5].y, a1[j]);
        a0[j] = fmaf(xhi.z, w[6].x, a0[j]); a1[j] = fmaf(xhi.z, w[6].y, a1[j]);
        a0[j] = fmaf(xhi.w, w[7].x, a0[j]); a1[j] = fmaf(xhi.w, w[7].y, a1[j]);
    }
}

// Depth-4 software-pipelined GEMM over NCH chunks of 8 K-rows.
template<int NCH, int NN, int XW>
__device__ __forceinline__ void gemm_pipe(const float* wp, const float (*X)[XW],
                                          int jbase, float* a0, float* a1)
{
    float2 w0[8], w1[8], w2[8], w3[8];
    ldw8(wp, w0); ldw8(wp, w1); ldw8(wp, w2);
    int d = 0;
    constexpr int IT = (NCH - 3) / 4;
    constexpr int L  = (NCH - 3) - 4 * IT;
    for (int it = 0; it < IT; ++it) {
        ldw8(wp, w3); fma8<NN, XW>(w0, X, jbase, d,      a0, a1);
        ldw8(wp, w0); fma8<NN, XW>(w1, X, jbase, d + 8,  a0, a1);
        ldw8(wp, w1); fma8<NN, XW>(w2, X, jbase, d + 16, a0, a1);
        ldw8(wp, w2); fma8<NN, XW>(w3, X, jbase, d + 24, a0, a1);
        d += 32;
    }
    if constexpr (L == 0) {
        fma8<NN, XW>(w0, X, jbase, d,      a0, a1);
        fma8<NN, XW>(w1, X, jbase, d + 8,  a0, a1);
        fma8<NN, XW>(w2, X, jbase, d + 16, a0, a1);
    } else if constexpr (L == 1) {
        ldw8(wp, w3);
        fma8<NN, XW>(w0, X, jbase, d,      a0, a1);
        fma8<NN, XW>(w1, X, jbase, d + 8,  a0, a1);
        fma8<NN, XW>(w2, X, jbase, d + 16, a0, a1);
        fma8<NN, XW>(w3, X, jbase, d + 24, a0, a1);
    } else if constexpr (L == 2) {
        ldw8(wp, w3); fma8<NN, XW>(w0, X, jbase, d,      a0, a1);
        ldw8(wp, w0); fma8<NN, XW>(w1, X, jbase, d + 8,  a0, a1);
        fma8<NN, XW>(w2, X, jbase, d + 16, a0, a1);
        fma8<NN, XW>(w3, X, jbase, d + 24, a0, a1);
        fma8<NN, XW>(w0, X, jbase, d + 32, a0, a1);
    } else {
        ldw8(wp, w3); fma8<NN, XW>(w0, X, jbase, d,      a0, a1);
        ldw8(wp, w0); fma8<NN, XW>(w1, X, jbase, d + 8,  a0, a1);
        ldw8(wp, w1); fma8<NN, XW>(w2, X, jbase, d + 16, a0, a1);
        fma8<NN, XW>(w3, X, jbase, d + 24, a0, a1);
        fma8<NN, XW>(w0, X, jbase, d + 32, a0, a1);
        fma8<NN, XW>(w1, X, jbase, d + 40, a0, a1);
    }
}

// tag_r[t][k] = br[k] + sum_j tag_table[t][j] * Wr[300+j][k]   (likewise tag_z)
__global__ __launch_bounds__(320) void tag_kernel(
    const float* __restrict__ tag_table,
    const float* __restrict__ Wr, const float* __restrict__ br,
    const float* __restrict__ Wz, const float* __restrict__ bz,
    float* __restrict__ tag_r, float* __restrict__ tag_z)
{
    int t = blockIdx.x;
    int k = threadIdx.x;
    __shared__ float te[50];
    if (k < 50) te[k] = tag_table[t * 50 + k];
    __syncthreads();
    if (k < H) {
        float ar = br[k], az = bz[k];
        #pragma unroll 10
        for (int j = 0; j < 50; ++j) {
            float tv = te[j];
            ar = fmaf(tv, Wr[(H + j) * H + k], ar);
            az = fmaf(tv, Wz[(H + j) * H + k], az);
        }
        tag_r[t * H + k] = ar;
        tag_z[t * H + k] = az;
    }
}

// Leaf: lh=rh=0 => r unused; h = (1-z)*u
template<int NB>
__global__ __launch_bounds__(NTHR, 1) void leaf_k(
    const int* __restrict__ word_ids, const int* __restrict__ tag_ids,
    const float* __restrict__ word_table,
    const float* __restrict__ Wz, const float* __restrict__ Wu,
    const float* __restrict__ bu, const float* __restrict__ tag_z,
    float* __restrict__ out)
{
    __shared__ float X[NB][H + 4];    // 304 floats; [300..303] zeroed
    __shared__ float Zs[NB][H + 4];
    int node0 = blockIdx.x * NB;
    int tid = threadIdx.x;

    for (int idx = tid; idx < NB * 75; idx += NTHR) {
        int j = idx / 75, q = idx - j * 75;
        *(float4*)&X[j][q * 4] =
            *(const float4*)&word_table[(long)word_ids[node0 + j] * H + q * 4];
    }
    if (tid < NB) *(float4*)&X[tid][H] = make_float4(0.f, 0.f, 0.f, 0.f);
    __syncthreads();

    int t = tid;
    int isu = (t >= 150);
    int c0 = 2 * (t - 150 * isu);
    float acc0[NB], acc1[NB];
    if (t < 300) {
        #pragma unroll
        for (int j = 0; j < NB; ++j) { acc0[j] = 0.f; acc1[j] = 0.f; }
        gemm_pipe<38, NB, H + 4>((isu ? Wu : Wz) + c0, X, 0, acc0, acc1);
        if (!isu) {
            #pragma unroll
            for (int j = 0; j < NB; ++j) {
                int tg = tag_ids[node0 + j];
                Zs[j][c0]     = sigmoidf_(acc0[j] + tag_z[tg * H + c0]);
                Zs[j][c0 + 1] = sigmoidf_(acc1[j] + tag_z[tg * H + c0 + 1]);
            }
        }
    }
    __syncthreads();
    if (t >= 150 && t < 300) {
        float b0 = bu[c0], b1 = bu[c0 + 1];
        #pragma unroll
        for (int j = 0; j < NB; ++j) {
            float u0 = tanhf(acc0[j] + b0);
            float u1 = tanhf(acc1[j] + b1);
            float h0 = (1.f - Zs[j][c0]) * u0;
            float h1 = (1.f - Zs[j][c0 + 1]) * u1;
            *(float2*)&out[(long)(node0 + j) * H + c0] = make_float2(h0, h1);
        }
    }
}

// Internal big-level kernel (unchanged from round 7).
template<int NB>
__global__ __launch_bounds__(NTHR, 1) void level_k(
    const int* __restrict__ tag_ids,
    const float* __restrict__ Wr, const float* __restrict__ Wz,
    const float* __restrict__ Wu, const float* __restrict__ bu,
    const float* __restrict__ tag_r, const float* __restrict__ tag_z,
    float* __restrict__ out, int off, int prevOff)
{
    __shared__ float X[NB][2 * H + 8];
    __shared__ float Ss[NB][H + 4];
    __shared__ float Zs[NB][H + 4];
    int node0 = blockIdx.x * NB;
    int tid = threadIdx.x;

    for (int idx = tid; idx < NB * 150; idx += NTHR) {
        int j = idx / 150, q = idx - j * 150;
        int half = q / 75, qq = q - half * 75;
        *(float4*)&X[j][half * H + qq * 4] =
            *(const float4*)&out[(long)(prevOff + 2 * (node0 + j) + half) * H + qq * 4];
    }
    __syncthreads();

    int t = tid;
    int isz = (t >= 150);
    int c0 = 2 * (t - 150 * isz);
    float acc0[NB], acc1[NB];
    if (t < 300) {
        #pragma unroll
        for (int j = 0; j < NB; ++j) { acc0[j] = 0.f; acc1[j] = 0.f; }
        gemm_pipe<75, NB, 2 * H + 8>(((isz ? Wz : Wr) + 350 * H) + c0, X, 0, acc0, acc1);
    }
    __syncthreads();

    if (t < 300) {
        if (!isz) {
            #pragma unroll
            for (int j = 0; j < NB; ++j) {
                int tg = tag_ids[off + node0 + j];
                float r0 = sigmoidf_(acc0[j] + tag_r[tg * H + c0]);
                float r1 = sigmoidf_(acc1[j] + tag_r[tg * H + c0 + 1]);
                float l0 = X[j][c0], l1 = X[j][c0 + 1];
                float q0 = X[j][H + c0], q1 = X[j][H + c0 + 1];
                Ss[j][c0]     = l0 + q0;
                Ss[j][c0 + 1] = l1 + q1;
                X[j][c0]     = r0 * l0;  X[j][c0 + 1] = r1 * l1;
                X[j][H + c0] = r0 * q0;  X[j][H + c0 + 1] = r1 * q1;
            }
        } else {
            #pragma unroll
            for (int j = 0; j < NB; ++j) {
                int tg = tag_ids[off + node0 + j];
                Zs[j][c0]     = sigmoidf_(acc0[j] + tag_z[tg * H + c0]);
                Zs[j][c0 + 1] = sigmoidf_(acc1[j] + tag_z[tg * H + c0 + 1]);
            }
        }
    }
    __syncthreads();

    constexpr int NBB = (NB > 1) ? NB / 2 : 1;
    int jb = (NB > 1) ? isz * NBB : 0;
    bool actB = (t < 300) && (NB > 1 || !isz);
    if (actB) {
        float b0a[NBB], b1a[NBB];
        #pragma unroll
        for (int jj = 0; jj < NBB; ++jj) { b0a[jj] = 0.f; b1a[jj] = 0.f; }
        gemm_pipe<75, NBB, 2 * H + 8>((Wu + 300 * H) + c0, X, jb, b0a, b1a);
        float bb0 = bu[c0], bb1 = bu[c0 + 1];
        #pragma unroll
        for (int jj = 0; jj < NBB; ++jj) {
            int j = jb + jj;
            float u0 = tanhf(b0a[jj] + bb0);
            float u1 = tanhf(b1a[jj] + bb1);
            float z0 = Zs[j][c0], z1 = Zs[j][c0 + 1];
            float h0 = z0 * Ss[j][c0]     + (1.f - z0) * u0;
            float h1 = z1 * Ss[j][c0 + 1] + (1.f - z1) * u1;
            *(float2*)&out[(long)(off + node0 + j) * H + c0] = make_float2(h0, h1);
        }
    }
}

// ---------------- Tail (m<=256): column+K-parallel, 2 kernels per level ----
// Block = one node x one 150-col slice (grid = 2m). Inside: 4 K-groups of
// 75 colpair-threads; chain = 19 chunks (vs 75), LDS reduce across groups.

// T1: r,z gates. Writes zbuf[n][c], sbuf[n][c]=lh+rh, rxbuf[n][0:600]=[r*lh|r*rh].
__global__ __launch_bounds__(320, 1) void tail_gates_k(
    const int* __restrict__ tag_ids,
    const float* __restrict__ Wr, const float* __restrict__ Wz,
    const float* __restrict__ tag_r, const float* __restrict__ tag_z,
    const float* __restrict__ out,
    float* __restrict__ zbuf, float* __restrict__ sbuf, float* __restrict__ rxbuf,
    int off, int prevOff)
{
    __shared__ float X[608];
    __shared__ float redR[3][152];
    __shared__ float redZ[3][152];
    int n  = blockIdx.x >> 1;
    int sl = blockIdx.x & 1;
    int tid = threadIdx.x;

    for (int i = tid; i < 150; i += 320) {
        int half = i / 75, q = i - half * 75;
        *(float4*)&X[half * 300 + q * 4] =
            *(const float4*)&out[(long)(prevOff + 2 * n + half) * H + q * 4];
    }
    __syncthreads();

    int kg = tid / 75;
    int pc = tid - kg * 75;
    bool act = (tid < 300);
    int c0 = sl * 150 + 2 * pc;
    float a0r = 0.f, a1r = 0.f, a0z = 0.f, a1z = 0.f;
    if (act) {
        int ch0 = kg * 19, ch1 = (kg == 3) ? 75 : ch0 + 19;
        const float* wr = Wr + 350 * H + c0;
        const float* wz = Wz + 350 * H + c0;
        for (int ch = ch0; ch < ch1; ++ch) {
            int k = ch * 8;
            float2 wrv[8], wzv[8];
            #pragma unroll
            for (int i = 0; i < 8; ++i) {
                wrv[i] = *(const float2*)&wr[(k + i) * H];
                wzv[i] = *(const float2*)&wz[(k + i) * H];
            }
            #pragma unroll
            for (int i = 0; i < 8; ++i) {
                float xv = X[k + i];
                a0r = fmaf(xv, wrv[i].x, a0r); a1r = fmaf(xv, wrv[i].y, a1r);
                a0z = fmaf(xv, wzv[i].x, a0z); a1z = fmaf(xv, wzv[i].y, a1z);
            }
        }
        if (kg > 0) {
            redR[kg - 1][2 * pc] = a0r; redR[kg - 1][2 * pc + 1] = a1r;
            redZ[kg - 1][2 * pc] = a0z; redZ[kg - 1][2 * pc + 1] = a1z;
        }
    }
    __syncthreads();
    if (act && kg == 0) {
        a0r += redR[0][2 * pc] + redR[1][2 * pc] + redR[2][2 * pc];
        a1r += redR[0][2 * pc + 1] + redR[1][2 * pc + 1] + redR[2][2 * pc + 1];
        a0z += redZ[0][2 * pc] + redZ[1][2 * pc] + redZ[2][2 * pc];
        a1z += redZ[0][2 * pc + 1] + redZ[1][2 * pc + 1] + redZ[2][2 * pc + 1];
        int tg = tag_ids[off + n];
        float r0 = sigmoidf_(a0r + tag_r[tg * H + c0]);
        float r1 = sigmoidf_(a1r + tag_r[tg * H + c0 + 1]);
        float z0 = sigmoidf_(a0z + tag_z[tg * H + c0]);
        float z1 = sigmoidf_(a1z + tag_z[tg * H + c0 + 1]);
        float l0 = X[c0], l1 = X[c0 + 1];
        float q0 = X[300 + c0], q1 = X[300 + c0 + 1];
        *(float2*)&zbuf[n * 304 + c0]  = make_float2(z0, z1);
        *(float2*)&sbuf[n * 304 + c0]  = make_float2(l0 + q0, l1 + q1);
        *(float2*)&rxbuf[n * 608 + c0]       = make_float2(r0 * l0, r1 * l1);
        *(float2*)&rxbuf[n * 608 + 300 + c0] = make_float2(r0 * q0, r1 * q1);
    }
}

// T2: u + h. Reads rxbuf/zbuf/sbuf, writes out (and dup for final state).
__global__ __launch_bounds__(320, 1) void tail_u_k(
    const float* __restrict__ Wu, const float* __restrict__ bu,
    const float* __restrict__ zbuf, const float* __restrict__ sbuf,
    const float* __restrict__ rxbuf,
    float* __restrict__ out, int off, float* __restrict__ dup)
{
    __shared__ float RX[608];
    __shared__ float redU[3][152];
    int n  = blockIdx.x >> 1;
    int sl = blockIdx.x & 1;
    int tid = threadIdx.x;

    for (int i = tid; i < 150; i += 320) {
        int half = i / 75, q = i - half * 75;
        *(float4*)&RX[half * 300 + q * 4] =
            *(const float4*)&rxbuf[n * 608 + half * 300 + q * 4];
    }
    __syncthreads();

    int kg = tid / 75;
    int pc = tid - kg * 75;
    bool act = (tid < 300);
    int c0 = sl * 150 + 2 * pc;
    float a0 = 0.f, a1 = 0.f;
    if (act) {
        int ch0 = kg * 19, ch1 = (kg == 3) ? 75 : ch0 + 19;
        const float* wu = Wu + 300 * H + c0;
        for (int ch = ch0; ch < ch1; ++ch) {
            int k = ch * 8;
            float2 wv[8];
            #pragma unroll
            for (int i = 0; i < 8; ++i) wv[i] = *(const float2*)&wu[(k + i) * H];
            #pragma unroll
            for (int i = 0; i < 8; ++i) {
                float xv = RX[k + i];
                a0 = fmaf(xv, wv[i].x, a0); a1 = fmaf(xv, wv[i].y, a1);
            }
        }
        if (kg > 0) { redU[kg - 1][2 * pc] = a0; redU[kg - 1][2 * pc + 1] = a1; }
    }
    __syncthreads();
    if (act && kg == 0) {
        a0 += redU[0][2 * pc] + redU[1][2 * pc] + redU[2][2 * pc];
        a1 += redU[0][2 * pc + 1] + redU[1][2 * pc + 1] + redU[2][2 * pc + 1];
        float u0 = tanhf(a0 + bu[c0]);
        float u1 = tanhf(a1 + bu[c0 + 1]);
        float z0 = zbuf[n * 304 + c0], z1 = zbuf[n * 304 + c0 + 1];
        float h0 = z0 * sbuf[n * 304 + c0]     + (1.f - z0) * u0;
        float h1 = z1 * sbuf[n * 304 + c0 + 1] + (1.f - z1) * u1;
        *(float2*)&out[(long)(off + n) * H + c0] = make_float2(h0, h1);
        if (dup && n == 0)
            *(float2*)&dup[c0] = make_float2(h0, h1);
    }
}

extern "C" void kernel_launch(void* const* d_in, const int* in_sizes, int n_in,
                              void* d_out, int out_size, void* d_ws, size_t ws_size,
                              hipStream_t stream)
{
    const int*   word_ids   = (const int*)  d_in[0];
    const int*   tag_ids    = (const int*)  d_in[1];
    const float* word_table = (const float*)d_in[2];
    const float* tag_table  = (const float*)d_in[3];
    const float* Wr         = (const float*)d_in[4];
    const float* br         = (const float*)d_in[5];
    const float* Wz         = (const float*)d_in[6];
    const float* bz         = (const float*)d_in[7];
    const float* Wu         = (const float*)d_in[8];
    const float* bu         = (const float*)d_in[9];
    float* out = (float*)d_out;

    float* tag_r = (float*)d_ws;           // 60*300
    float* tag_z = tag_r + 60 * H;         // 60*300
    float* zbuf  = tag_z + 60 * H;         // 256*304
    float* sbuf  = zbuf + 256 * 304;       // 256*304
    float* rxbuf = sbuf + 256 * 304;       // 256*608

    tag_kernel<<<60, 320, 0, stream>>>(tag_table, Wr, br, Wz, bz, tag_r, tag_z);

    leaf_k<8><<<NLEAF / 8, NTHR, 0, stream>>>(
        word_ids, tag_ids, word_table, Wz, Wu, bu, tag_z, out);

    // Big internal levels: 2 blocks/CU (grid 512)
    level_k<4><<<512, NTHR, 0, stream>>>(tag_ids, Wr, Wz, Wu, bu, tag_r, tag_z, out, 4096, 0);
    level_k<2><<<512, NTHR, 0, stream>>>(tag_ids, Wr, Wz, Wu, bu, tag_r, tag_z, out, 6144, 4096);
    level_k<1><<<512, NTHR, 0, stream>>>(tag_ids, Wr, Wz, Wu, bu, tag_r, tag_z, out, 7168, 6144);

    // Tail levels m=256..1: two column+K-parallel kernels per level
    float* finalDup = out + (long)8191 * H;
    int off = 7680, prevOff = 7168;
    for (int m = 256; m >= 1; m >>= 1) {
        tail_gates_k<<<2 * m, 320, 0, stream>>>(
            tag_ids, Wr, Wz, tag_r, tag_z, out, zbuf, sbuf, rxbuf, off, prevOff);
        tail_u_k<<<2 * m, 320, 0, stream>>>(
            Wu, bu, zbuf, sbuf, rxbuf, out, off, (m == 1) ? finalDup : nullptr);
        prevOff = off;
        off += m;
    }
}